// Round 14
// baseline (152.211 us; speedup 1.0000x reference)
//
#include <hip/hip_runtime.h>
#include <cstddef>

#define S_LEN 4096
#define C_DIM 256
#define NHEADS 8
#define HDIM 32

typedef __attribute__((ext_vector_type(8))) _Float16 half8;
typedef __attribute__((ext_vector_type(4))) _Float16 half4;
typedef __attribute__((ext_vector_type(2))) _Float16 h2t;
typedef __attribute__((ext_vector_type(2))) __fp16 fp16x2;
typedef __attribute__((ext_vector_type(4))) float floatx4;

// scale * log2(e) folded into W_q and bias_q at prep time
#define SC2F ((float)(0.17677669529663687 * 1.4426950408889634))

// ---------------------------------------------------------------- prep + GN partial stats
__global__ __launch_bounds__(256) void prep_stats(
    const float* __restrict__ qkv_w, const float* __restrict__ proj_w,
    const float* __restrict__ qkv_b, const float* __restrict__ x,
    _Float16* __restrict__ wq, _Float16* __restrict__ wp,
    float* __restrict__ qbias, float* __restrict__ pstat)
{
  const int blk = blockIdx.x;
  const int tid = threadIdx.x;
  if (blk < 512) {
    __shared__ float red[2][4];
    const int gb = blk >> 3, e = blk & 7;       // gb = b*32+g
    const int g = gb & 31, b = gb >> 5;
    const float* xb = x + ((size_t)b * C_DIM + g * 8) * S_LEN + e * 4096;
    const float4* x4 = (const float4*)xb;       // 1024 float4
    float sum = 0.f, sumsq = 0.f;
    #pragma unroll
    for (int i = 0; i < 4; ++i) {
      float4 v = x4[tid + i * 256];
      sum += v.x + v.y + v.z + v.w;
      sumsq += v.x * v.x + v.y * v.y + v.z * v.z + v.w * v.w;
    }
    for (int off = 1; off < 64; off <<= 1) {
      sum += __shfl_xor(sum, off, 64);
      sumsq += __shfl_xor(sumsq, off, 64);
    }
    const int wv = tid >> 6, lane = tid & 63;
    if (lane == 0) { red[0][wv] = sum; red[1][wv] = sumsq; }
    __syncthreads();
    if (tid == 0) {
      pstat[(gb * 8 + e) * 2 + 0] = red[0][0] + red[0][1] + red[0][2] + red[0][3];
      pstat[(gb * 8 + e) * 2 + 1] = red[1][0] + red[1][1] + red[1][2] + red[1][3];
    }
  } else {
    int idx = (blk - 512) * 256 + tid;
    if (idx < 768 * 256) {
      float v = qkv_w[idx];
      if (idx < 256 * 256) v *= SC2F;          // q rows
      wq[idx] = (_Float16)v;
    } else if (idx < 768 * 256 + 256 * 256) {
      int i = idx - 768 * 256;
      wp[i] = (_Float16)proj_w[i];
    } else if (idx < 768 * 256 + 256 * 256 + 768) {
      int i = idx - (768 * 256 + 256 * 256);
      float bv = qkv_b[i];
      if (i < 256) bv *= SC2F;
      qbias[i] = bv;
    }
  }
}

// ---------------------------------------------------------------- QKV GEMM + inline GN
// 32-s tiles, grid (2,128,2): x read only 2x. Wave owns 6 mt-tiles (96 W
// rows): 12 MFMA per 2 ds_read_b128. bx=1 holds all v rows (LDS-staged).
__global__ __launch_bounds__(256) void qkv_gn_gemm(
    const _Float16* __restrict__ W, const float* __restrict__ bias,
    const float* __restrict__ x, const float* __restrict__ gamma,
    const float* __restrict__ beta, const float* __restrict__ pstat,
    _Float16* __restrict__ qo, _Float16* __restrict__ ko_,
    _Float16* __restrict__ vo)
{
  __shared__ __align__(16) _Float16 Ld[32 * 264];   // [s][c], 16.9 KB
  __shared__ __align__(16) _Float16 VLd[256 * 36];  // v-stage, 18.4 KB
  const int tid = threadIdx.x;
  const int b = blockIdx.z;
  const int s0 = blockIdx.y * 32;

  {  // ---- inline GN apply: x (c,s) -> Ld[s][c] f16 (32-s tile)
    const int c0 = (tid & 127) * 2, c1 = c0 + 1;
    const int sh = tid >> 7;                         // s-half 0/1 (16 s each)
    const int g = c0 >> 3;
    const int gb = b * 32 + g;
    float s = 0.f, sq = 0.f;
    #pragma unroll
    for (int e = 0; e < 8; ++e) {
      s  += pstat[(gb * 8 + e) * 2 + 0];
      sq += pstat[(gb * 8 + e) * 2 + 1];
    }
    const float mean = s * (1.f / 32768.f);
    const float rstd = rsqrtf(sq * (1.f / 32768.f) - mean * mean + 1e-6f);
    const float ga0 = gamma[c0] * rstd, be0 = beta[c0] - mean * ga0;
    const float ga1 = gamma[c1] * rstd, be1 = beta[c1] - mean * ga1;
    const float4* xa = (const float4*)(x + ((size_t)b * C_DIM + c0) * S_LEN + s0 + sh * 16);
    const float4* xc = (const float4*)(x + ((size_t)b * C_DIM + c1) * S_LEN + s0 + sh * 16);
    #pragma unroll
    for (int j = 0; j < 4; ++j) {
      float4 a = xa[j], c = xc[j];
      int sl = sh * 16 + j * 4;
      *(h2t*)&Ld[(sl + 0) * 264 + c0] = (h2t){ (_Float16)(a.x * ga0 + be0), (_Float16)(c.x * ga1 + be1) };
      *(h2t*)&Ld[(sl + 1) * 264 + c0] = (h2t){ (_Float16)(a.y * ga0 + be0), (_Float16)(c.y * ga1 + be1) };
      *(h2t*)&Ld[(sl + 2) * 264 + c0] = (h2t){ (_Float16)(a.z * ga0 + be0), (_Float16)(c.z * ga1 + be1) };
      *(h2t*)&Ld[(sl + 3) * 264 + c0] = (h2t){ (_Float16)(a.w * ga0 + be0), (_Float16)(c.w * ga1 + be1) };
    }
  }
  __syncthreads();

  const int lane = tid & 63, wv = tid >> 6;
  const int m = lane & 15, quad = lane >> 4;
  const int mtb = blockIdx.x * 24 + wv * 6;     // 6 mt tiles per wave
  const _Float16* lp = &Ld[m * 264 + quad * 8];
  const _Float16* wr[6];
  #pragma unroll
  for (int j = 0; j < 6; ++j)
    wr[j] = W + (size_t)((mtb + j) * 16 + m) * C_DIM + quad * 8;

  floatx4 acc[6][2];
  #pragma unroll
  for (int j = 0; j < 6; ++j) {
    acc[j][0] = (floatx4){0.f,0.f,0.f,0.f};
    acc[j][1] = (floatx4){0.f,0.f,0.f,0.f};
  }

  #pragma unroll
  for (int k0 = 0; k0 < C_DIM; k0 += 32) {
    half8 b0 = *(const half8*)(lp + k0);
    half8 b1 = *(const half8*)(lp + 16 * 264 + k0);
    #pragma unroll
    for (int j = 0; j < 6; ++j) {
      half8 a = *(const half8*)(wr[j] + k0);
      acc[j][0] = __builtin_amdgcn_mfma_f32_16x16x32_f16(a, b0, acc[j][0], 0, 0, 0);
      acc[j][1] = __builtin_amdgcn_mfma_f32_16x16x32_f16(a, b1, acc[j][1], 0, 0, 0);
    }
  }

  #pragma unroll
  for (int j = 0; j < 6; ++j) {
    const int ob = (mtb + j) * 16 + quad * 4;
    const float bv0 = bias[ob], bv1 = bias[ob + 1],
                bv2 = bias[ob + 2], bv3 = bias[ob + 3];
    #pragma unroll
    for (int sub = 0; sub < 2; ++sub) {
      float v0 = acc[j][sub][0] + bv0, v1 = acc[j][sub][1] + bv1,
            v2 = acc[j][sub][2] + bv2, v3 = acc[j][sub][3] + bv3;
      if (ob < 512) {                       // q or k: coalesced half4 stores
        int s = s0 + sub * 16 + m;
        half4 h = { (_Float16)v0, (_Float16)v1, (_Float16)v2, (_Float16)v3 };
        _Float16* dst = (ob < 256) ? qo : ko_;
        int oo = ob & 255, n = oo >> 5, d0 = oo & 31;
        *(half4*)(dst + (((size_t)b * NHEADS + n) * S_LEN + s) * HDIM + d0) = h;
      } else {                              // v: stage to VLd [row 0..255][36]
        int vr = ob - 512;
        int s = sub * 16 + m;
        VLd[(vr + 0) * 36 + s] = (_Float16)v0;
        VLd[(vr + 1) * 36 + s] = (_Float16)v1;
        VLd[(vr + 2) * 36 + s] = (_Float16)v2;
        VLd[(vr + 3) * 36 + s] = (_Float16)v3;
      }
    }
  }
  if (blockIdx.x == 1) {                    // all 256 v-rows live here
    __syncthreads();
    const int row = tid;                    // v channel 0..255
    const int n = row >> 5, d = row & 31;
    _Float16* dst = vo + ((size_t)(b * NHEADS + n) * HDIM + d) * S_LEN + s0;
    const _Float16* src = VLd + row * 36;
    *(half8*)(dst + 0)  = *(const half8*)(src + 0);
    *(half8*)(dst + 8)  = *(const half8*)(src + 8);
    *(half8*)(dst + 16) = *(const half8*)(src + 16);
    *(half8*)(dst + 24) = *(const half8*)(src + 24);
  }
}

// ---------------------------------------------------------------- Attention (R13, unchanged)
__global__ __launch_bounds__(512) void attn_kernel(
    const _Float16* __restrict__ q, const _Float16* __restrict__ k,
    const _Float16* __restrict__ v, _Float16* __restrict__ po,
    float* __restrict__ pl)
{
  __shared__ __align__(16) _Float16 Kl[2][64 * 40];  // (kk, d) stride 40
  __shared__ __align__(16) _Float16 Vl[2][32 * 68];  // (d, kk) stride 68
  const int tid = threadIdx.x;
  const int lane = tid & 63, wv = tid >> 6;          // wv 0..7
  const int m = lane & 15, quad = lane >> 4;
  const int n = blockIdx.y, b = blockIdx.z;
  const int qc = blockIdx.x >> 1, kh = blockIdx.x & 1;
  const int q0 = qc * 256 + wv * 32;
  const int bh = b * NHEADS + n;

  const _Float16* qb = q + (size_t)bh * S_LEN * HDIM;
  const _Float16* kb = k + (size_t)bh * S_LEN * HDIM + (size_t)kh * 2048 * HDIM;
  const _Float16* vb = v + (size_t)bh * HDIM * S_LEN + (size_t)kh * 2048;

  half8 qfA = *(const half8*)(qb + (size_t)(q0 + m) * HDIM + quad * 8);
  half8 qfB = *(const half8*)(qb + (size_t)(q0 + 16 + m) * HDIM + quad * 8);

  const int krow = wv * 8 + (lane >> 3), kc = (lane & 7) * 4;
  const int vrow = wv * 4 + (lane >> 4), vc = (lane & 15) * 4;
  const _Float16* kg = kb + (size_t)krow * HDIM + kc;
  const _Float16* vg = vb + (size_t)vrow * S_LEN + vc;
  const int klds = krow * 40 + kc;
  const int vlds = vrow * 68 + vc;

  int2 kreg = *(const int2*)kg;
  int2 vreg = *(const int2*)vg;
  const _Float16* kgp = kg + 64 * HDIM;
  const _Float16* vgp = vg + 64;

  floatx4 oA0 = {0.f,0.f,0.f,0.f}, oA1 = oA0, oB0 = oA0, oB1 = oA0;
  float lA = 0.f, lB = 0.f;
  const fp16x2 one2 = { (__fp16)1.0f, (__fp16)1.0f };

  #pragma unroll 2
  for (int it = 0; it < 32; ++it) {          // 32 x 64 keys = 2048 (half)
    const int bufi = it & 1;
    *(int2*)(&Kl[bufi][klds]) = kreg;
    *(int2*)(&Vl[bufi][vlds]) = vreg;
    kreg = *(const int2*)kgp; kgp += 64 * HDIM;   // unconditional prefetch
    vreg = *(const int2*)vgp; vgp += 64;
    __syncthreads();
    const _Float16* Kb = Kl[bufi];
    const _Float16* Vb = Vl[bufi];
    #pragma unroll
    for (int t = 0; t < 4; ++t) {
      half8 kf = *(const half8*)(Kb + (t * 16 + m) * 40 + quad * 8);
      half4 vf0 = *(const half4*)(Vb + m * 68 + t * 16 + quad * 4);
      half4 vf1 = *(const half4*)(Vb + (16 + m) * 68 + t * 16 + quad * 4);
      floatx4 z = {0.f,0.f,0.f,0.f};
      floatx4 sA = __builtin_amdgcn_mfma_f32_16x16x32_f16(kf, qfA, z, 0, 0, 0);
      floatx4 sB = __builtin_amdgcn_mfma_f32_16x16x32_f16(kf, qfB, z, 0, 0, 0);
      float eA0 = __builtin_amdgcn_exp2f(sA[0]);
      float eA1 = __builtin_amdgcn_exp2f(sA[1]);
      float eA2 = __builtin_amdgcn_exp2f(sA[2]);
      float eA3 = __builtin_amdgcn_exp2f(sA[3]);
      float eB0 = __builtin_amdgcn_exp2f(sB[0]);
      float eB1 = __builtin_amdgcn_exp2f(sB[1]);
      float eB2 = __builtin_amdgcn_exp2f(sB[2]);
      float eB3 = __builtin_amdgcn_exp2f(sB[3]);
      half4 pA, pB;
      fp16x2 pAlo = __builtin_amdgcn_cvt_pkrtz(eA0, eA1);
      fp16x2 pAhi = __builtin_amdgcn_cvt_pkrtz(eA2, eA3);
      fp16x2 pBlo = __builtin_amdgcn_cvt_pkrtz(eB0, eB1);
      fp16x2 pBhi = __builtin_amdgcn_cvt_pkrtz(eB2, eB3);
      *(fp16x2*)&pA = pAlo; *((fp16x2*)&pA + 1) = pAhi;
      *(fp16x2*)&pB = pBlo; *((fp16x2*)&pB + 1) = pBhi;
      lA = __builtin_amdgcn_fdot2(pAlo, one2, lA, false);
      lA = __builtin_amdgcn_fdot2(pAhi, one2, lA, false);
      lB = __builtin_amdgcn_fdot2(pBlo, one2, lB, false);
      lB = __builtin_amdgcn_fdot2(pBhi, one2, lB, false);
      oA0 = __builtin_amdgcn_mfma_f32_16x16x16f16(vf0, pA, oA0, 0, 0, 0);
      oA1 = __builtin_amdgcn_mfma_f32_16x16x16f16(vf1, pA, oA1, 0, 0, 0);
      oB0 = __builtin_amdgcn_mfma_f32_16x16x16f16(vf0, pB, oB0, 0, 0, 0);
      oB1 = __builtin_amdgcn_mfma_f32_16x16x16f16(vf1, pB, oB1, 0, 0, 0);
    }
  }
  lA += __shfl_xor(lA, 16, 64); lA += __shfl_xor(lA, 32, 64);
  lB += __shfl_xor(lB, 16, 64); lB += __shfl_xor(lB, 32, 64);
  _Float16* pobase = po + (size_t)kh * 2097152 + ((size_t)bh * S_LEN) * HDIM;
  {
    _Float16* poh = pobase + (size_t)(q0 + m) * HDIM;
    half4 h0 = { (_Float16)oA0[0], (_Float16)oA0[1], (_Float16)oA0[2], (_Float16)oA0[3] };
    half4 h1 = { (_Float16)oA1[0], (_Float16)oA1[1], (_Float16)oA1[2], (_Float16)oA1[3] };
    *(half4*)(poh + quad * 4) = h0;
    *(half4*)(poh + 16 + quad * 4) = h1;
    if (quad == 0) pl[(size_t)kh * 65536 + (size_t)bh * S_LEN + q0 + m] = lA;
  }
  {
    _Float16* poh = pobase + (size_t)(q0 + 16 + m) * HDIM;
    half4 h0 = { (_Float16)oB0[0], (_Float16)oB0[1], (_Float16)oB0[2], (_Float16)oB0[3] };
    half4 h1 = { (_Float16)oB1[0], (_Float16)oB1[1], (_Float16)oB1[2], (_Float16)oB1[3] };
    *(half4*)(poh + quad * 4) = h0;
    *(half4*)(poh + 16 + quad * 4) = h1;
    if (quad == 0) pl[(size_t)kh * 65536 + (size_t)bh * S_LEN + q0 + 16 + m] = lB;
  }
}

// ---------------------------------------------------------------- Proj GEMM (+ fused merge)
// 32-s tiles, grid (2,128,2): po read only 2x. Wave owns 2 mt-tiles.
__global__ __launch_bounds__(256) void proj_gemm(
    const _Float16* __restrict__ W, const float* __restrict__ bias,
    const _Float16* __restrict__ po, const float* __restrict__ pl,
    const float* __restrict__ x, float* __restrict__ out)
{
  __shared__ float Linv[256];                // [n][s_local 32]
  const int tid = threadIdx.x;
  const int lane = tid & 63, wv = tid >> 6;
  const int m = lane & 15, quad = lane >> 4;
  const int mtb = blockIdx.x * 8 + wv * 2;   // 2 mt tiles per wave
  const int s0 = blockIdx.y * 32;
  const int b = blockIdx.z;

  {
    const int nn = tid >> 5, jj = tid & 31;
    size_t base = (size_t)(b * NHEADS + nn) * S_LEN + s0 + jj;
    Linv[nn * 32 + jj] = 1.f / (pl[base] + pl[65536 + base]);
  }
  __syncthreads();

  const _Float16* wr0 = W + (size_t)((mtb + 0) * 16 + m) * C_DIM + quad * 8;
  const _Float16* wr1 = W + (size_t)((mtb + 1) * 16 + m) * C_DIM + quad * 8;
  floatx4 acc[2][2];
  acc[0][0] = (floatx4){0.f,0.f,0.f,0.f}; acc[0][1] = acc[0][0];
  acc[1][0] = acc[0][0]; acc[1][1] = acc[0][0];

  #pragma unroll
  for (int k0 = 0; k0 < C_DIM; k0 += 32) {
    const int n = k0 >> 5;
    const int d0 = quad * 8;
    half8 bf[2];
    #pragma unroll
    for (int sub = 0; sub < 2; ++sub) {
      size_t idx = (((size_t)(b * NHEADS + n)) * S_LEN + s0 + sub * 16 + m) * HDIM + d0;
      half8 a = *(const half8*)(po + idx);
      half8 c = *(const half8*)(po + 2097152 + idx);
      _Float16 iv = (_Float16)Linv[n * 32 + sub * 16 + m];
      bf[sub] = (a + c) * iv;
    }
    half8 a0 = *(const half8*)(wr0 + k0);
    half8 a1 = *(const half8*)(wr1 + k0);
    acc[0][0] = __builtin_amdgcn_mfma_f32_16x16x32_f16(a0, bf[0], acc[0][0], 0, 0, 0);
    acc[0][1] = __builtin_amdgcn_mfma_f32_16x16x32_f16(a0, bf[1], acc[0][1], 0, 0, 0);
    acc[1][0] = __builtin_amdgcn_mfma_f32_16x16x32_f16(a1, bf[0], acc[1][0], 0, 0, 0);
    acc[1][1] = __builtin_amdgcn_mfma_f32_16x16x32_f16(a1, bf[1], acc[1][1], 0, 0, 0);
  }
  #pragma unroll
  for (int j = 0; j < 2; ++j) {
    #pragma unroll
    for (int sub = 0; sub < 2; ++sub) {
      int s = s0 + sub * 16 + m;
      #pragma unroll
      for (int r = 0; r < 4; ++r) {
        int c = (mtb + j) * 16 + quad * 4 + r;
        size_t idx = ((size_t)b * C_DIM + c) * S_LEN + s;
        out[idx] = x[idx] + acc[j][sub][r] + bias[c];
      }
    }
  }
}

// ---------------------------------------------------------------- launch
extern "C" void kernel_launch(void* const* d_in, const int* in_sizes, int n_in,
                              void* d_out, int out_size, void* d_ws, size_t ws_size,
                              hipStream_t stream) {
  const float* x        = (const float*)d_in[0];
  const float* gn_gamma = (const float*)d_in[1];
  const float* gn_beta  = (const float*)d_in[2];
  const float* qkv_w    = (const float*)d_in[3];
  const float* qkv_b    = (const float*)d_in[4];
  const float* proj_w   = (const float*)d_in[5];
  const float* proj_b   = (const float*)d_in[6];
  float* out = (float*)d_out;

  const size_t n1 = (size_t)2 * S_LEN * C_DIM;   // 2M elems = 4 MB f16
  char* ws = (char*)d_ws;
  _Float16* qx  = (_Float16*)ws;                 // (B,NH,S,hd)
  _Float16* kx  = qx + n1;                       // (B,NH,S,hd)
  _Float16* vx  = kx + n1;                       // (B,NH,hd,S)
  _Float16* wq  = vx + n1;                       // 768x256 f16
  _Float16* wp  = wq + 768 * 256;                // 256x256 f16
  float*    qbias = (float*)(wp + 256 * 256);    // 768 f32
  float*    pstat = qbias + 768;                 // 64*8*2 f32 = 4 KB
  _Float16* po  = (_Float16*)(pstat + 1024);     // 2 x 2M f16 = 8 MB
  float*    pl  = (float*)(po + 2 * n1);         // 2 x 64K f32 = 512 KB

  prep_stats<<<1539, 256, 0, stream>>>(qkv_w, proj_w, qkv_b, x, wq, wp, qbias, pstat);
  qkv_gn_gemm<<<dim3(2, 128, 2), 256, 0, stream>>>(wq, qbias, x, gn_gamma, gn_beta, pstat, qx, kx, vx);
  attn_kernel<<<dim3(32, 8, 2), 512, 0, stream>>>(qx, kx, vx, po, pl);
  proj_gemm<<<dim3(2, 128, 2), 256, 0, stream>>>(wp, proj_b, po, pl, x, out);
}